// Round 1
// baseline (1004.007 us; speedup 1.0000x reference)
//
#include <hip/hip_runtime.h>
#include <math.h>

#define N_ROWS 131072
#define DIM 64
#define KC 64
#define NBLK 512
#define ROWS_PB 256
#define NTILE 4

// scratch layout inside d_out's "compressed" region (float offsets).
// compressed region is [0, 8388608); kernel C overwrites it LAST, after all
// scratch uses are done. clusters_out at 8388608, attn_out at 8392704.
#define PARTIAL_OFF 0u               // 512*64*64 = 2097152 floats
#define SUMA_OFF    2097152u         // 512*64    = 32768 floats
#define WSQ_OFF     4194304u         // 131072 floats
#define CUR_OFF     4325376u         // 4096 floats
#define NEWC_OFF    4329472u         // 4096 floats
#define NORM_BYTE_OFF (4333568ull * 4ull)  // 64 doubles, 8B aligned

__global__ __launch_bounds__(256) void rowsq_kernel(const float* __restrict__ W,
                                                    float* __restrict__ wsq) {
  int r = blockIdx.x * 256 + threadIdx.x;
  const float4* p = (const float4*)(W + (size_t)r * DIM);
  float s0 = 0.f, s1 = 0.f, s2 = 0.f, s3 = 0.f;
#pragma unroll
  for (int c = 0; c < 16; ++c) {
    float4 v = p[c];
    s0 = fmaf(v.x, v.x, s0);
    s1 = fmaf(v.y, v.y, s1);
    s2 = fmaf(v.z, v.z, s2);
    s3 = fmaf(v.w, v.w, s3);
  }
  wsq[r] = (s0 + s1) + (s2 + s3);
}

// One k-means iteration: distances -> softmax attn -> per-block partial sums
// of attn^T * W and column-sums of attn. Deterministic (no atomics).
__global__ __launch_bounds__(256) void dkm_iter(
    const float* __restrict__ W, const float* __restrict__ Cin,
    const float* __restrict__ wsq, float* __restrict__ partial,
    float* __restrict__ sumA, float* __restrict__ attn_out, int writeAttn) {
  __shared__ float Csh[64 * 64];
  __shared__ float Wsh[64 * 64];
  __shared__ float Ash[64 * 64];
  __shared__ float csq[64];
  __shared__ float saq[256];

  const int t = threadIdx.x;
  const int blk = blockIdx.x;
  const int rowBase = blk * ROWS_PB;

  float4* Csh4 = (float4*)Csh;
  float4* Wsh4 = (float4*)Wsh;
  float4* Ash4 = (float4*)Ash;

  // stage clusters, XOR-swizzled: 16B-chunk index ^= (row>>2)&15
  {
    const float4* gC = (const float4*)Cin;
#pragma unroll
    for (int q = 0; q < 4; ++q) {
      int m = t + 256 * q;
      Csh4[m ^ ((m >> 6) & 15)] = gC[m];
    }
  }
  __syncthreads();
  if (t < 64) {
    float s = 0.f;
#pragma unroll
    for (int c = 0; c < 16; ++c) {
      float4 v = Csh4[(t * 16 + c) ^ ((t >> 2) & 15)];
      s += v.x * v.x + v.y * v.y + v.z * v.z + v.w * v.w;
    }
    csq[t] = s;
  }
  __syncthreads();

  const int rg = t >> 4;  // phase1: row-group (4 rows). phase2: k-group (4 ks).
  const int kg = t & 15;  // phase1: k-group (4 ks).   phase2: d-group (4 ds).

  float acc2[4][4] = {{0.f}};
  float sa_acc = 0.f;
  const int sks = t & 63;  // sumA: k index
  const int sq = t >> 6;   // sumA: row quarter

  for (int tile = 0; tile < NTILE; ++tile) {
    // stage W tile (swizzled)
    {
      const float4* gW = (const float4*)(W + (size_t)(rowBase + tile * 64) * DIM);
#pragma unroll
      for (int q = 0; q < 4; ++q) {
        int m = t + 256 * q;
        Wsh4[m ^ ((m >> 6) & 15)] = gW[m];
      }
    }
    __syncthreads();

    // phase 1: 4x4 block of S = W*C^T
    float dot[4][4] = {{0.f}};
#pragma unroll 4
    for (int c = 0; c < 16; ++c) {
      float4 wv[4], cv[4];
#pragma unroll
      for (int i = 0; i < 4; ++i) wv[i] = Wsh4[((rg * 4 + i) * 16 + c) ^ rg];
#pragma unroll
      for (int j = 0; j < 4; ++j) cv[j] = Csh4[((kg * 4 + j) * 16 + c) ^ kg];
#pragma unroll
      for (int i = 0; i < 4; ++i)
#pragma unroll
        for (int j = 0; j < 4; ++j) {
          float d0 = fmaf(wv[i].x, cv[j].x, dot[i][j]);
          d0 = fmaf(wv[i].y, cv[j].y, d0);
          d0 = fmaf(wv[i].z, cv[j].z, d0);
          dot[i][j] = fmaf(wv[i].w, cv[j].w, d0);
        }
    }

    // softmax over k (16 lanes * 4 local) -> at[4][4]
    float at[4][4];
#pragma unroll
    for (int i = 0; i < 4; ++i) {
      float w2 = wsq[rowBase + tile * 64 + rg * 4 + i];
      float lg[4];
      float mx = -3.4e38f;
#pragma unroll
      for (int j = 0; j < 4; ++j) {
        float d2 = w2 + csq[kg * 4 + j] - 2.f * dot[i][j];
        d2 = fmaxf(d2, 0.f);
        lg[j] = -sqrtf(d2);
        mx = fmaxf(mx, lg[j]);
      }
      mx = fmaxf(mx, __shfl_xor(mx, 1));
      mx = fmaxf(mx, __shfl_xor(mx, 2));
      mx = fmaxf(mx, __shfl_xor(mx, 4));
      mx = fmaxf(mx, __shfl_xor(mx, 8));
      float s = 0.f;
#pragma unroll
      for (int j = 0; j < 4; ++j) {
        float e = expf(lg[j] - mx);
        at[i][j] = e;
        s += e;
      }
      s += __shfl_xor(s, 1);
      s += __shfl_xor(s, 2);
      s += __shfl_xor(s, 4);
      s += __shfl_xor(s, 8);
      float inv = 1.f / s;
#pragma unroll
      for (int j = 0; j < 4; ++j) at[i][j] *= inv;
    }

    // attn tile -> LDS (unswizzled [row][kchunk])
#pragma unroll
    for (int i = 0; i < 4; ++i)
      Ash4[(rg * 4 + i) * 16 + kg] = make_float4(at[i][0], at[i][1], at[i][2], at[i][3]);
    __syncthreads();

    if (writeAttn) {
      float4* gA = (float4*)(attn_out + (size_t)(rowBase + tile * 64) * KC);
#pragma unroll
      for (int q = 0; q < 4; ++q) {
        int m = t + 256 * q;
        gA[m] = Ash4[m];
      }
    }

    // phase 2: acc2[kj][dm] += attn[r][k0+kj] * W[r][d0+dm]
#pragma unroll 8
    for (int r = 0; r < 64; ++r) {
      float4 av = Ash4[r * 16 + rg];
      float4 wv = Wsh4[(r * 16 + kg) ^ ((r >> 2) & 15)];
      acc2[0][0] = fmaf(av.x, wv.x, acc2[0][0]);
      acc2[0][1] = fmaf(av.x, wv.y, acc2[0][1]);
      acc2[0][2] = fmaf(av.x, wv.z, acc2[0][2]);
      acc2[0][3] = fmaf(av.x, wv.w, acc2[0][3]);
      acc2[1][0] = fmaf(av.y, wv.x, acc2[1][0]);
      acc2[1][1] = fmaf(av.y, wv.y, acc2[1][1]);
      acc2[1][2] = fmaf(av.y, wv.z, acc2[1][2]);
      acc2[1][3] = fmaf(av.y, wv.w, acc2[1][3]);
      acc2[2][0] = fmaf(av.z, wv.x, acc2[2][0]);
      acc2[2][1] = fmaf(av.z, wv.y, acc2[2][1]);
      acc2[2][2] = fmaf(av.z, wv.z, acc2[2][2]);
      acc2[2][3] = fmaf(av.z, wv.w, acc2[2][3]);
      acc2[3][0] = fmaf(av.w, wv.x, acc2[3][0]);
      acc2[3][1] = fmaf(av.w, wv.y, acc2[3][1]);
      acc2[3][2] = fmaf(av.w, wv.z, acc2[3][2]);
      acc2[3][3] = fmaf(av.w, wv.w, acc2[3][3]);
    }
    // sumA partial (reads Ash, still valid until next loop-top sync)
#pragma unroll
    for (int rr = 0; rr < 16; ++rr) sa_acc += Ash[(sq * 16 + rr) * 64 + sks];
    __syncthreads();  // protect Wsh/Ash before next tile's staging
  }

  // per-block partials
#pragma unroll
  for (int j = 0; j < 4; ++j) {
    float4 v = make_float4(acc2[j][0], acc2[j][1], acc2[j][2], acc2[j][3]);
    ((float4*)partial)[((size_t)blk * 64 + rg * 4 + j) * 16 + kg] = v;
  }
  saq[t] = sa_acc;
  __syncthreads();
  if (t < 64) sumA[blk * 64 + t] = saq[t] + saq[t + 64] + saq[t + 128] + saq[t + 192];
}

// Reduce 512 block partials -> newC (f64 accumulate), per-k norm partials.
__global__ __launch_bounds__(256) void reduce_kernel(
    const float* __restrict__ partial, const float* __restrict__ sumAp,
    const float* __restrict__ curC, float* __restrict__ newC,
    double* __restrict__ normpart) {
  int k = blockIdx.x;
  int t = threadIdx.x;
  int d = t & 63, q = t >> 6;
  double acc = 0.0;
  for (int b = q * 128; b < q * 128 + 128; ++b)
    acc += (double)partial[((size_t)b * 64 + k) * 64 + d];
  __shared__ double sh[256];
  __shared__ double sh2[256];
  sh[t] = acc;
  sh2[t] = (double)sumAp[(2 * t) * 64 + k] + (double)sumAp[(2 * t + 1) * 64 + k];
  __syncthreads();
  for (int s = 128; s >= 1; s >>= 1) {
    if (t < s) sh2[t] += sh2[t + s];
    __syncthreads();
  }
  if (t < 64) {
    double tot = sh[t] + sh[t + 64] + sh[t + 128] + sh[t + 192];
    float nc = (float)(tot / sh2[0]);
    newC[k * 64 + t] = nc;
    double diff = (double)curC[k * 64 + t] - (double)nc;
    sh[t] = diff * diff;
  }
  __syncthreads();
  if (t == 0) {
    double s = 0.0;
    for (int i = 0; i < 64; ++i) s += sh[i];
    normpart[k] = s;
  }
}

// Gate the update on ||cur - new||_F > eps (equivalent to ref's done flag,
// since a frozen state reproduces itself bitwise).
__global__ __launch_bounds__(256) void select_kernel(
    const double* __restrict__ normpart, const float* __restrict__ newC,
    const float* __restrict__ prevC, float* __restrict__ cur,
    float* __restrict__ clusters_out, int writeOut) {
  __shared__ int cond_sh;
  int t = threadIdx.x;
  if (t == 0) {
    double s = 0.0;
    for (int i = 0; i < 64; ++i) s += normpart[i];
    cond_sh = (sqrt(s) > 1.0e-4) ? 1 : 0;
  }
  __syncthreads();
  int cond = cond_sh;
  for (int m = t; m < 4096; m += 256) {
    float v = cond ? newC[m] : prevC[m];
    cur[m] = v;
    if (writeOut) clusters_out[m] = v;
  }
}

// compressed = attn @ clusters
__global__ __launch_bounds__(256) void compress_kernel(
    const float* __restrict__ attn, const float* __restrict__ Cl,
    float* __restrict__ outC) {
  __shared__ float Csh[64 * 64];
  __shared__ float Ash[64 * 64];
  float4* Csh4 = (float4*)Csh;
  float4* Ash4 = (float4*)Ash;
  const int t = threadIdx.x;
  const int blk = blockIdx.x;
  const int rowBase = blk * ROWS_PB;
  const int rg = t >> 4, dg = t & 15;

  {
    const float4* gC = (const float4*)Cl;
#pragma unroll
    for (int q = 0; q < 4; ++q) {
      int m = t + 256 * q;
      Csh4[m ^ ((m >> 6) & 15)] = gC[m];
    }
  }

  for (int tile = 0; tile < NTILE; ++tile) {
    __syncthreads();  // Csh ready (1st iter) + Ash reuse protection
    {
      const float4* gA = (const float4*)(attn + (size_t)(rowBase + tile * 64) * KC);
#pragma unroll
      for (int q = 0; q < 4; ++q) {
        int m = t + 256 * q;
        Ash4[m ^ ((m >> 6) & 15)] = gA[m];
      }
    }
    __syncthreads();
    float acc[4][4] = {{0.f}};
#pragma unroll 4
    for (int c = 0; c < 16; ++c) {
      float4 av[4], cv[4];
#pragma unroll
      for (int i = 0; i < 4; ++i) av[i] = Ash4[((rg * 4 + i) * 16 + c) ^ rg];
#pragma unroll
      for (int j = 0; j < 4; ++j) cv[j] = Csh4[((c * 4 + j) * 16 + dg) ^ c];
#pragma unroll
      for (int i = 0; i < 4; ++i) {
        float a0 = fmaf(av[i].x, cv[0].x, acc[i][0]);
        a0 = fmaf(av[i].y, cv[1].x, a0);
        a0 = fmaf(av[i].z, cv[2].x, a0);
        acc[i][0] = fmaf(av[i].w, cv[3].x, a0);
        float a1 = fmaf(av[i].x, cv[0].y, acc[i][1]);
        a1 = fmaf(av[i].y, cv[1].y, a1);
        a1 = fmaf(av[i].z, cv[2].y, a1);
        acc[i][1] = fmaf(av[i].w, cv[3].y, a1);
        float a2 = fmaf(av[i].x, cv[0].z, acc[i][2]);
        a2 = fmaf(av[i].y, cv[1].z, a2);
        a2 = fmaf(av[i].z, cv[2].z, a2);
        acc[i][2] = fmaf(av[i].w, cv[3].z, a2);
        float a3 = fmaf(av[i].x, cv[0].w, acc[i][3]);
        a3 = fmaf(av[i].y, cv[1].w, a3);
        a3 = fmaf(av[i].z, cv[2].w, a3);
        acc[i][3] = fmaf(av[i].w, cv[3].w, a3);
      }
    }
    float4* gO = (float4*)(outC + (size_t)(rowBase + tile * 64) * DIM);
#pragma unroll
    for (int i = 0; i < 4; ++i)
      gO[(rg * 4 + i) * 16 + dg] = make_float4(acc[i][0], acc[i][1], acc[i][2], acc[i][3]);
  }
}

extern "C" void kernel_launch(void* const* d_in, const int* in_sizes, int n_in,
                              void* d_out, int out_size, void* d_ws, size_t ws_size,
                              hipStream_t stream) {
  (void)in_sizes; (void)n_in; (void)d_ws; (void)ws_size; (void)out_size;
  const float* W = (const float*)d_in[0];
  const float* Cinit = (const float*)d_in[1];
  float* ob = (float*)d_out;

  float* compressed = ob;                       // [N, D]
  float* clusters_out = ob + (size_t)N_ROWS * DIM;   // [K, D]
  float* attn_out = ob + (size_t)N_ROWS * DIM + KC * DIM;  // [N, K]

  float* partial = ob + PARTIAL_OFF;
  float* sumAp = ob + SUMA_OFF;
  float* wsq = ob + WSQ_OFF;
  float* cur = ob + CUR_OFF;
  float* newC = ob + NEWC_OFF;
  double* normpart = (double*)((char*)d_out + NORM_BYTE_OFF);

  rowsq_kernel<<<NBLK, 256, 0, stream>>>(W, wsq);

  for (int it = 0; it < 10; ++it) {
    const float* Cptr = (it == 0) ? Cinit : cur;
    dkm_iter<<<NBLK, 256, 0, stream>>>(W, Cptr, wsq, partial, sumAp, attn_out,
                                       (it == 9) ? 1 : 0);
    reduce_kernel<<<64, 256, 0, stream>>>(partial, sumAp, Cptr, newC, normpart);
    select_kernel<<<1, 256, 0, stream>>>(normpart, newC, Cptr, cur, clusters_out,
                                         (it == 9) ? 1 : 0);
  }
  compress_kernel<<<NBLK, 256, 0, stream>>>(attn_out, clusters_out, compressed);
}

// Round 4
// 587.948 us; speedup vs baseline: 1.7076x; 1.7076x over previous
//
#include <hip/hip_runtime.h>
#include <math.h>
#include <stdint.h>

#define N_ROWS 131072
#define DIM 64
#define KC 64
#define NBLK 512
#define ROWS_PB 256

typedef __attribute__((ext_vector_type(8))) short short8;
typedef __attribute__((ext_vector_type(8))) unsigned short ushort8;
typedef __attribute__((ext_vector_type(16))) float float16;
typedef __attribute__((ext_vector_type(4))) unsigned int uint4v;
typedef __attribute__((ext_vector_type(2))) unsigned long long ulong2v;

// scratch layout inside d_out's "compressed" region (floats [0, 8388608)).
// compress kernel runs LAST and reads only attn_out/clusters_out (outside).
#define WT_BYTE_OFF 0ull                   // 64*131072 ushorts = 16 MB
#define PARTIAL_OFF 4194304u               // 512*64*64 floats
#define SUMA_OFF    6291456u               // 512*64 floats
#define WSQ_OFF     6324224u               // 131072 floats
#define CUR_OFF     6455296u               // 4096 floats
#define NEWC_OFF    6459392u               // 4096 floats
#define NORM_BYTE_OFF (6463488ull * 4ull)  // 128 doubles

// round-to-nearest-even bf16 (unbiased, unlike truncation)
__device__ __forceinline__ uint32_t rne16(float a) {
  uint32_t u = __float_as_uint(a);
  return (u + 0x7fffu + ((u >> 16) & 1u)) >> 16;
}

__device__ __forceinline__ uint32_t pack_bf16(float a, float b) {
  return rne16(a) | (rne16(b) << 16);
}

// split f32 pair -> packed bf16 hi dword and lo dword, both RNE:
// x = hi + lo + eps, |eps| <= 2^-17 |x| (RNE hi gives |lo| <= 2^-9|x|)
__device__ __forceinline__ void split2(float a, float b, uint32_t& hi, uint32_t& lo) {
  uint32_t ha = rne16(a), hb = rne16(b);
  hi = ha | (hb << 16);
  float la = a - __uint_as_float(ha << 16);
  float lb = b - __uint_as_float(hb << 16);
  lo = pack_bf16(la, lb);
}

// prep: wsq[r] = ||W[r]||^2  and  WT[d][n] = bf16_rne(W[n][d]) (transposed copy)
__global__ __launch_bounds__(256) void prep_kernel(const float* __restrict__ W,
                                                   float* __restrict__ wsq,
                                                   unsigned short* __restrict__ WT) {
  __shared__ unsigned short Tsh[64][256];
  const int t = threadIdx.x;
  const int blk = blockIdx.x;
  const int r = blk * 256 + t;
  const float4* p = (const float4*)(W + (size_t)r * DIM);
  float s = 0.f;
#pragma unroll
  for (int c = 0; c < 16; ++c) {
    float4 v = p[c];
    s += v.x * v.x + v.y * v.y + v.z * v.z + v.w * v.w;
    Tsh[c * 4 + 0][t] = (unsigned short)rne16(v.x);
    Tsh[c * 4 + 1][t] = (unsigned short)rne16(v.y);
    Tsh[c * 4 + 2][t] = (unsigned short)rne16(v.z);
    Tsh[c * 4 + 3][t] = (unsigned short)rne16(v.w);
  }
  wsq[r] = s;
  __syncthreads();
#pragma unroll
  for (int it = 0; it < 8; ++it) {
    const int idx = it * 256 + t;
    const int d = idx >> 5, c8 = (idx & 31) * 8;
    ushort8 v = *(const ushort8*)&Tsh[d][c8];
    *(ushort8*)(WT + (size_t)d * N_ROWS + blk * 256 + c8) = v;
  }
}

// One k-means iteration, MFMA-based. Grid 512 x 256 threads (4 waves).
// Block owns 256 rows = 2 rounds x 4 chunks of 32 rows; wave w does phase1
// (dist+softmax) for chunk w of each round, then all waves do phase2
// (attn^T * W), each owning one 32x32 quadrant of the 64x64 update.
// Also applies the previous iteration's cluster select (idempotent
// duplicate writes of identical bytes to curbuf -> race-free).
__global__ __launch_bounds__(256, 2) void dkm_iter(
    const float* __restrict__ W, const unsigned short* __restrict__ WT,
    const float* __restrict__ Cinit, const float* __restrict__ wsq,
    const float* __restrict__ newC, float* __restrict__ curbuf,
    const double* __restrict__ normpart,
    float* __restrict__ partial, float* __restrict__ sumA,
    float* __restrict__ attn_out, int useSel, int writeAttn)
{
  __shared__ __align__(16) short CbfHi[64][68];      // clusters hi bf16, padded
  __shared__ __align__(16) short CbfLo[64][68];      // clusters lo bf16
  __shared__ __align__(16) short attnT[4][64 * 36];  // attn^T bf16 [k][row], padded
  __shared__ float csqL[64];
  __shared__ float wsqL[128];
  __shared__ float red[256];
  __shared__ int s_cond;

  const int t = threadIdx.x;
  const int blk = blockIdx.x;
  const int wid = t >> 6;
  const int lane = t & 63;
  const int l31 = lane & 31;
  const int lh = lane >> 5;
  const int rowBase = blk * ROWS_PB;

  // ---- previous-iteration convergence gate (wave 0, butterfly f64) ----
  if (wid == 0) {
    double v = useSel ? (normpart[lane] + normpart[64 + lane]) : 0.0;
    v += __shfl_xor(v, 1); v += __shfl_xor(v, 2); v += __shfl_xor(v, 4);
    v += __shfl_xor(v, 8); v += __shfl_xor(v, 16); v += __shfl_xor(v, 32);
    if (lane == 0) s_cond = (v > 1.0e-8) ? 1 : 0;  // ||.||_F > 1e-4
  }
  __syncthreads();
  const float* src = useSel ? (s_cond ? newC : curbuf) : Cinit;

  // ---- stage clusters: hi/lo split into LDS, csq partials, write curbuf ----
  {
    const int row = t >> 2, c0 = (t & 3) * 16;
    float sq = 0.f;
#pragma unroll
    for (int q = 0; q < 4; ++q) {
      float4 v = *(const float4*)(src + row * 64 + c0 + q * 4);
      *(float4*)(curbuf + row * 64 + c0 + q * 4) = v;  // idempotent dup write
      uint32_t h0, h1, l0, l1;
      split2(v.x, v.y, h0, l0);
      split2(v.z, v.w, h1, l1);
      *(uint32_t*)&CbfHi[row][c0 + q * 4] = h0;
      *(uint32_t*)&CbfHi[row][c0 + q * 4 + 2] = h1;
      *(uint32_t*)&CbfLo[row][c0 + q * 4] = l0;
      *(uint32_t*)&CbfLo[row][c0 + q * 4 + 2] = l1;
      sq += v.x * v.x + v.y * v.y + v.z * v.z + v.w * v.w;
    }
    red[t] = sq;
  }
  __syncthreads();
  if (t < 64) csqL[t] = (red[4 * t] + red[4 * t + 1]) + (red[4 * t + 2] + red[4 * t + 3]);

  float16 Uacc = {0,0,0,0, 0,0,0,0, 0,0,0,0, 0,0,0,0};
  float sa0 = 0.f, sa1 = 0.f;
  const int mg = wid >> 1, ng = wid & 1;

  for (int rnd = 0; rnd < 2; ++rnd) {
    const int chunkBase = rowBase + rnd * 128;

    if (t < 128) wsqL[t] = wsq[chunkBase + t];
    __syncthreads();  // wsqL ready; csqL ready (1st round); attnT reusable

    // ---- phase 1: dist + softmax for wave's own chunk (rows wid*32..+31) ----
    const int rowA = chunkBase + wid * 32 + l31;  // A-frag: m = lane&31
    float16 dot0 = {0,0,0,0, 0,0,0,0, 0,0,0,0, 0,0,0,0};
    float16 dot1 = {0,0,0,0, 0,0,0,0, 0,0,0,0, 0,0,0,0};
#pragma unroll
    for (int ko = 0; ko < 4; ++ko) {
      const float* pw = W + (size_t)rowA * 64 + ko * 16 + lh * 8;
      float4 x0 = *(const float4*)pw;
      float4 x1 = *(const float4*)(pw + 4);
      uint32_t h0, h1, h2, h3, l0, l1, l2, l3;
      split2(x0.x, x0.y, h0, l0); split2(x0.z, x0.w, h1, l1);
      split2(x1.x, x1.y, h2, l2); split2(x1.z, x1.w, h3, l3);
      uint4v th = {h0, h1, h2, h3};
      uint4v tl = {l0, l1, l2, l3};
      short8 aHi = __builtin_bit_cast(short8, th);
      short8 aLo = __builtin_bit_cast(short8, tl);
#pragma unroll
      for (int nt = 0; nt < 2; ++nt) {
        const unsigned long long* ph = (const unsigned long long*)&CbfHi[nt * 32 + l31][ko * 16 + lh * 8];
        const unsigned long long* pl = (const unsigned long long*)&CbfLo[nt * 32 + l31][ko * 16 + lh * 8];
        ulong2v vh = {ph[0], ph[1]};
        ulong2v vl = {pl[0], pl[1]};
        short8 cHi = __builtin_bit_cast(short8, vh);
        short8 cLo = __builtin_bit_cast(short8, vl);
        float16& dd = (nt == 0) ? dot0 : dot1;
        dd = __builtin_amdgcn_mfma_f32_32x32x16_bf16(aHi, cHi, dd, 0, 0, 0);
        dd = __builtin_amdgcn_mfma_f32_32x32x16_bf16(aLo, cHi, dd, 0, 0, 0);
        dd = __builtin_amdgcn_mfma_f32_32x32x16_bf16(aHi, cLo, dd, 0, 0, 0);
      }
    }

    // softmax over k (64 = 2 tiles x 32 lanes); D-layout row formula (m74/m101)
    const float cq0 = csqL[l31], cq1 = csqL[32 + l31];
#pragma unroll
    for (int j = 0; j < 16; ++j) {
      const int trow = (j & 3) + 8 * (j >> 2) + 4 * lh;
      const float w2 = wsqL[wid * 32 + trow];
      float g0 = -sqrtf(fmaxf(w2 + cq0 - 2.f * dot0[j], 0.f));
      float g1 = -sqrtf(fmaxf(w2 + cq1 - 2.f * dot1[j], 0.f));
      float mj = fmaxf(g0, g1);
      mj = fmaxf(mj, __shfl_xor(mj, 1));  mj = fmaxf(mj, __shfl_xor(mj, 2));
      mj = fmaxf(mj, __shfl_xor(mj, 4));  mj = fmaxf(mj, __shfl_xor(mj, 8));
      mj = fmaxf(mj, __shfl_xor(mj, 16));
      float e0 = __expf(g0 - mj), e1 = __expf(g1 - mj);
      float sj = e0 + e1;
      sj += __shfl_xor(sj, 1);  sj += __shfl_xor(sj, 2);  sj += __shfl_xor(sj, 4);
      sj += __shfl_xor(sj, 8);  sj += __shfl_xor(sj, 16);
      float inv = __builtin_amdgcn_rcpf(sj);
      float a0 = e0 * inv, a1 = e1 * inv;
      sa0 += a0; sa1 += a1;
      dot0[j] = a0; dot1[j] = a1;
      if (writeAttn) {
        attn_out[(size_t)(chunkBase + wid * 32 + trow) * 64 + l31] = a0;
        attn_out[(size_t)(chunkBase + wid * 32 + trow) * 64 + 32 + l31] = a1;
      }
    }
    // attn -> attnT bf16 RNE (transposed: [cluster][row]) for phase2 A-frags
    {
      uint32_t* aT = (uint32_t*)&attnT[wid][0];
#pragma unroll
      for (int h = 0; h < 4; ++h) {
        const int base = 4 * h + 2 * lh;  // dword offset: rows 8h+4lh+(0..3)
        aT[l31 * 18 + base]     = pack_bf16(dot0[4 * h],     dot0[4 * h + 1]);
        aT[l31 * 18 + base + 1] = pack_bf16(dot0[4 * h + 2], dot0[4 * h + 3]);
        aT[(32 + l31) * 18 + base]     = pack_bf16(dot1[4 * h],     dot1[4 * h + 1]);
        aT[(32 + l31) * 18 + base + 1] = pack_bf16(dot1[4 * h + 2], dot1[4 * h + 3]);
      }
    }
    __syncthreads();

    // ---- phase 2: U[quadrant mg,ng] += attn^T * W over the round's 4 chunks
    // B-frag from the transposed bf16 copy WT[d][row]: contiguous 16B loads,
    // k-order identical to attnT's by construction.
#pragma unroll
    for (int c = 0; c < 4; ++c) {
#pragma unroll
      for (int kc = 0; kc < 2; ++kc) {
        const unsigned long long* pa =
            (const unsigned long long*)&attnT[c][(mg * 32 + l31) * 36 + kc * 16 + lh * 8];
        ulong2v va = {pa[0], pa[1]};
        short8 af = __builtin_bit_cast(short8, va);
        const unsigned short* pwT =
            WT + (size_t)(ng * 32 + l31) * N_ROWS + (chunkBase + c * 32 + kc * 16 + lh * 8);
        ushort8 wv = *(const ushort8*)pwT;
        short8 bf = __builtin_bit_cast(short8, wv);
        Uacc = __builtin_amdgcn_mfma_f32_32x32x16_bf16(af, bf, Uacc, 0, 0, 0);
      }
    }
    __syncthreads();  // before next round rewrites wsqL/attnT
  }

  // ---- epilogue: per-block partial of attn^T W (wave-owned quadrant) ----
#pragma unroll
  for (int j = 0; j < 16; ++j) {
    const int k = mg * 32 + (j & 3) + 8 * (j >> 2) + 4 * lh;
    partial[((size_t)blk * 64 + k) * 64 + ng * 32 + l31] = Uacc[j];
  }
  // sumA: fold halves then cross-wave via LDS
  sa0 += __shfl_xor(sa0, 32);
  sa1 += __shfl_xor(sa1, 32);
  if (lane < 32) {
    red[wid * 64 + l31] = sa0;
    red[wid * 64 + 32 + l31] = sa1;
  }
  __syncthreads();
  if (t < 64) sumA[blk * 64 + t] = (red[t] + red[64 + t]) + (red[128 + t] + red[192 + t]);
}

// Reduce 512 block partials -> newC (f64), norm partials. 128 blocks: (k, dhalf).
__global__ __launch_bounds__(256) void reduce_kernel(
    const float* __restrict__ partial, const float* __restrict__ sumAp,
    const float* __restrict__ curC, float* __restrict__ newC,
    double* __restrict__ normpart) {
  const int k = blockIdx.x >> 1, dh = blockIdx.x & 1;
  const int t = threadIdx.x;
  const int d = dh * 32 + (t & 31), q = t >> 5;
  double acc = 0.0;
  for (int b = q * 64; b < q * 64 + 64; ++b)
    acc += (double)partial[((size_t)b * 64 + k) * 64 + d];
  __shared__ double sh[256];
  __shared__ double sh2[256];
  sh[t] = acc;
  sh2[t] = (double)sumAp[t * 64 + k] + (double)sumAp[(t + 256) * 64 + k];
  __syncthreads();
  for (int s = 128; s >= 1; s >>= 1) {
    if (t < s) sh2[t] += sh2[t + s];
    __syncthreads();
  }
  if (t < 32) {
    double tot = ((sh[t] + sh[t + 32]) + (sh[t + 64] + sh[t + 96])) +
                 ((sh[t + 128] + sh[t + 160]) + (sh[t + 192] + sh[t + 224]));
    float nc = (float)(tot / sh2[0]);
    newC[k * 64 + d] = nc;
    double diff = (double)curC[k * 64 + d] - (double)nc;
    sh[t] = diff * diff;
  }
  __syncthreads();
  if (t == 0) {
    double s = 0.0;
#pragma unroll
    for (int i = 0; i < 32; ++i) s += sh[i];
    normpart[blockIdx.x] = s;
  }
}

// Final select: clusters_out = (||cur9 - new9|| > eps) ? newC : cur
__global__ __launch_bounds__(256) void finalize_kernel(
    const double* __restrict__ np, const float* __restrict__ newC,
    const float* __restrict__ cur, float* __restrict__ clusters_out) {
  __shared__ double sh[64];
  __shared__ int sc;
  int t = threadIdx.x;
  if (t < 64) sh[t] = np[t] + np[t + 64];
  __syncthreads();
  if (t == 0) {
    double s = 0.0;
    for (int i = 0; i < 64; ++i) s += sh[i];
    sc = (s > 1.0e-8) ? 1 : 0;
  }
  __syncthreads();
  const float* src = sc ? newC : cur;
  for (int m = t; m < 4096; m += 256) clusters_out[m] = src[m];
}

// compressed = attn @ clusters  (exact f32; reads only attn_out/clusters_out)
__global__ __launch_bounds__(256) void compress_kernel(
    const float* __restrict__ attn, const float* __restrict__ Cl,
    float* __restrict__ outC) {
  __shared__ float Csh[64 * 64];
  __shared__ float Ash[64 * 64];
  float4* Csh4 = (float4*)Csh;
  float4* Ash4 = (float4*)Ash;
  const int t = threadIdx.x;
  const int blk = blockIdx.x;
  const int rowBase = blk * ROWS_PB;
  const int rg = t >> 4, dg = t & 15;

  {
    const float4* gC = (const float4*)Cl;
#pragma unroll
    for (int q = 0; q < 4; ++q) {
      int m = t + 256 * q;
      Csh4[m ^ ((m >> 6) & 15)] = gC[m];
    }
  }

  for (int tile = 0; tile < 4; ++tile) {
    __syncthreads();
    {
      const float4* gA = (const float4*)(attn + (size_t)(rowBase + tile * 64) * KC);
#pragma unroll
      for (int q = 0; q < 4; ++q) {
        int m = t + 256 * q;
        Ash4[m ^ ((m >> 6) & 15)] = gA[m];
      }
    }
    __syncthreads();
    float acc[4][4] = {{0.f}};
#pragma unroll 4
    for (int c = 0; c < 16; ++c) {
      float4 av[4], cv[4];
#pragma unroll
      for (int i = 0; i < 4; ++i) av[i] = Ash4[((rg * 4 + i) * 16 + c) ^ rg];
#pragma unroll
      for (int j = 0; j < 4; ++j) cv[j] = Csh4[((c * 4 + j) * 16 + dg) ^ c];
#pragma unroll
      for (int i = 0; i < 4; ++i) {
        float a0 = fmaf(av[i].x, cv[0].x, acc[i][0]);
        a0 = fmaf(av[i].y, cv[1].x, a0);
        a0 = fmaf(av[i].z, cv[2].x, a0);
        acc[i][0] = fmaf(av[i].w, cv[3].x, a0);
        float a1 = fmaf(av[i].x, cv[0].y, acc[i][1]);
        a1 = fmaf(av[i].y, cv[1].y, a1);
        a1 = fmaf(av[i].z, cv[2].y, a1);
        acc[i][1] = fmaf(av[i].w, cv[3].y, a1);
        float a2 = fmaf(av[i].x, cv[0].z, acc[i][2]);
        a2 = fmaf(av[i].y, cv[1].z, a2);
        a2 = fmaf(av[i].z, cv[2].z, a2);
        acc[i][2] = fmaf(av[i].w, cv[3].z, a2);
        float a3 = fmaf(av[i].x, cv[0].w, acc[i][3]);
        a3 = fmaf(av[i].y, cv[1].w, a3);
        a3 = fmaf(av[i].z, cv[2].w, a3);
        acc[i][3] = fmaf(av[i].w, cv[3].w, a3);
      }
    }
    float4* gO = (float4*)(outC + (size_t)(rowBase + tile * 64) * DIM);
#pragma unroll
    for (int i = 0; i < 4; ++i)
      gO[(rg * 4 + i) * 16 + dg] = make_float4(acc[i][0], acc[i][1], acc[i][2], acc[i][3]);
  }
}

extern "C" void kernel_launch(void* const* d_in, const int* in_sizes, int n_in,
                              void* d_out, int out_size, void* d_ws, size_t ws_size,
                              hipStream_t stream) {
  (void)in_sizes; (void)n_in; (void)d_ws; (void)ws_size; (void)out_size;
  const float* W = (const float*)d_in[0];
  const float* Cinit = (const float*)d_in[1];
  float* ob = (float*)d_out;

  float* compressed = ob;                                  // [N, D]
  float* clusters_out = ob + (size_t)N_ROWS * DIM;         // [K, D]
  float* attn_out = ob + (size_t)N_ROWS * DIM + KC * DIM;  // [N, K]

  unsigned short* WT = (unsigned short*)((char*)d_out + WT_BYTE_OFF);
  float* partial = ob + PARTIAL_OFF;
  float* sumAp = ob + SUMA_OFF;
  float* wsq = ob + WSQ_OFF;
  float* curbuf = ob + CUR_OFF;
  float* newC = ob + NEWC_OFF;
  double* normpart = (double*)((char*)d_out + NORM_BYTE_OFF);

  prep_kernel<<<NBLK, 256, 0, stream>>>(W, wsq, WT);

  for (int it = 0; it < 10; ++it) {
    dkm_iter<<<NBLK, 256, 0, stream>>>(W, WT, Cinit, wsq, newC, curbuf, normpart,
                                       partial, sumAp, attn_out,
                                       (it > 0) ? 1 : 0, (it == 9) ? 1 : 0);
    reduce_kernel<<<128, 256, 0, stream>>>(partial, sumAp, curbuf, newC, normpart);
  }
  finalize_kernel<<<1, 256, 0, stream>>>(normpart, newC, curbuf, clusters_out);
  compress_kernel<<<NBLK, 256, 0, stream>>>(attn_out, clusters_out, compressed);
}

// Round 6
// 450.558 us; speedup vs baseline: 2.2284x; 1.3049x over previous
//
#include <hip/hip_runtime.h>
#include <math.h>
#include <stdint.h>

#define N_ROWS 131072
#define DIM 64
#define KC 64
#define NBLK 512
#define ROWS_PB 256

typedef __attribute__((ext_vector_type(8))) short short8;
typedef __attribute__((ext_vector_type(8))) unsigned short ushort8;
typedef __attribute__((ext_vector_type(16))) float float16;
typedef __attribute__((ext_vector_type(4))) unsigned int uint4v;
typedef __attribute__((ext_vector_type(2))) unsigned long long ulong2v;

// scratch layout (float offsets into d_out's compressed region [0, 8388608)):
// WT bf16 [64][131072] = 16MB at byte 0; partial [512][64][64] f32 = 8MB;
// suma [512][64]; newC [64][64]; normpart 128 doubles.
// cur lives in the clusters_out region (ob + 8388608, 16KB exact).
// attn region untouched until iter 9; compress overwrites compressed last.
#define PARTIAL_OFF 4194304u
#define SUMA_OFF    6291456u
#define NEWC_OFF    6324224u
#define NORM_BYTE_OFF (6328320ull * 4ull)

// round-to-nearest-even bf16 (unbiased; truncation's random error is ~2x
// larger AND biased -> measured 7e-4 cluster error in r3/r5; RNE passes)
__device__ __forceinline__ uint32_t rne16(float a) {
  uint32_t u = __float_as_uint(a);
  return (u + 0x7fffu + ((u >> 16) & 1u)) >> 16;
}

__device__ __forceinline__ uint32_t pack_bf16(float a, float b) {
  return rne16(a) | (rne16(b) << 16);
}

// RNE split: x = hi + lo + eps, |lo| <= 2^-9|x|, |eps| <= 2^-17|x|, unbiased
__device__ __forceinline__ void split2(float a, float b, uint32_t& hi, uint32_t& lo) {
  uint32_t ha = rne16(a), hb = rne16(b);
  hi = ha | (hb << 16);
  float la = a - __uint_as_float(ha << 16);
  float lb = b - __uint_as_float(hb << 16);
  lo = pack_bf16(la, lb);
}

// prep: WT[d][n] = bf16_rne(W[n][d]) (transposed copy for phase-2 B-frags)
__global__ __launch_bounds__(256) void prep_kernel(const float* __restrict__ W,
                                                   unsigned short* __restrict__ WT) {
  __shared__ unsigned short Tsh[64][256];
  const int t = threadIdx.x;
  const int blk = blockIdx.x;
  const int r = blk * 256 + t;
  const float4* p = (const float4*)(W + (size_t)r * DIM);
#pragma unroll
  for (int c = 0; c < 16; ++c) {
    float4 v = p[c];
    Tsh[c * 4 + 0][t] = (unsigned short)rne16(v.x);
    Tsh[c * 4 + 1][t] = (unsigned short)rne16(v.y);
    Tsh[c * 4 + 2][t] = (unsigned short)rne16(v.z);
    Tsh[c * 4 + 3][t] = (unsigned short)rne16(v.w);
  }
  __syncthreads();
#pragma unroll
  for (int it = 0; it < 8; ++it) {
    const int idx = it * 256 + t;
    const int d = idx >> 5, c8 = (idx & 31) * 8;
    ushort8 v = *(const ushort8*)&Tsh[d][c8];
    *(ushort8*)(WT + (size_t)d * N_ROWS + blk * 256 + c8) = v;
  }
}

// One k-means iteration. 512 blocks x 512 threads (8 waves).
// Phase 1 (swapped): dot = mfma(A=clusters, B=W-rows) -> lane holds one row's
// cluster scores (half; partner lane^32 has the other half) -> register
// softmax with a single shfl_xor(32) for max and sum.
// Phase 2: U = attnT @ W via mfma(attnT-frag, WT-frag); 8 waves = 4 output
// quadrants x 2 k-row halves, combined through LDS.
__global__ __launch_bounds__(512, 4) void dkm_iter(
    const float* __restrict__ W, const unsigned short* __restrict__ WT,
    const float* __restrict__ Cinit,
    const float* __restrict__ newC, float* __restrict__ cur,
    const double* __restrict__ normpart,
    float* __restrict__ partial, float* __restrict__ sumA,
    float* __restrict__ attn_out, int useSel, int writeAttn)
{
  __shared__ __align__(16) short CbfHi[64][68];   // clusters hi bf16 (pad 68)
  __shared__ __align__(16) short CbfLo[64][68];   // clusters lo bf16
  __shared__ __align__(16) short attnT[64][264];  // attn^T bf16 [cl][row], pad
  __shared__ float csqL[64];
  __shared__ float red[512];
  __shared__ int s_cond;

  const int t = threadIdx.x;
  const int blk = blockIdx.x;
  const int wid = t >> 6, lane = t & 63, l31 = lane & 31, lh = lane >> 5;
  const int half = wid >> 2, quad = wid & 3, mg = quad >> 1, ng = quad & 1;
  const int rowBase = blk * ROWS_PB;
  const int myrow = rowBase + wid * 32 + l31;

  // ---- issue W row loads early (phase-1 B-frags; f32) ----
  const float* pw = W + (size_t)myrow * 64 + lh * 8;
  float4 wv0 = *(const float4*)(pw);      float4 wv1 = *(const float4*)(pw + 4);
  float4 wv2 = *(const float4*)(pw + 16); float4 wv3 = *(const float4*)(pw + 20);
  float4 wv4 = *(const float4*)(pw + 32); float4 wv5 = *(const float4*)(pw + 36);
  float4 wv6 = *(const float4*)(pw + 48); float4 wv7 = *(const float4*)(pw + 52);

  // ---- previous-iteration convergence gate (wave 0) ----
  if (wid == 0) {
    double v = useSel ? (normpart[lane] + normpart[64 + lane]) : 0.0;
    v += __shfl_xor(v, 1); v += __shfl_xor(v, 2); v += __shfl_xor(v, 4);
    v += __shfl_xor(v, 8); v += __shfl_xor(v, 16); v += __shfl_xor(v, 32);
    if (lane == 0) s_cond = (v > 1.0e-8) ? 1 : 0;  // ||.||_F > 1e-4
  }
  // w2 = ||W[myrow]||^2 from the loaded halves (+ partner half)
  float w2 = wv0.x*wv0.x + wv0.y*wv0.y + wv0.z*wv0.z + wv0.w*wv0.w
           + wv1.x*wv1.x + wv1.y*wv1.y + wv1.z*wv1.z + wv1.w*wv1.w
           + wv2.x*wv2.x + wv2.y*wv2.y + wv2.z*wv2.z + wv2.w*wv2.w
           + wv3.x*wv3.x + wv3.y*wv3.y + wv3.z*wv3.z + wv3.w*wv3.w
           + wv4.x*wv4.x + wv4.y*wv4.y + wv4.z*wv4.z + wv4.w*wv4.w
           + wv5.x*wv5.x + wv5.y*wv5.y + wv5.z*wv5.z + wv5.w*wv5.w
           + wv6.x*wv6.x + wv6.y*wv6.y + wv6.z*wv6.z + wv6.w*wv6.w
           + wv7.x*wv7.x + wv7.y*wv7.y + wv7.z*wv7.z + wv7.w*wv7.w;
  w2 += __shfl_xor(w2, 32);
  __syncthreads();  // s_cond ready

  const float* src = useSel ? (s_cond ? newC : cur) : Cinit;

  // ---- stage clusters (RNE split hi/lo), csq via 8-lane shfl, cur write ----
  {
    const int crow = t >> 3, cc = (t & 7) * 8;
    float4 c0 = *(const float4*)(src + crow * 64 + cc);
    float4 c1 = *(const float4*)(src + crow * 64 + cc + 4);
    if (blk == 0) {  // single-block cur update (idempotent when src==cur)
      *(float4*)(cur + crow * 64 + cc) = c0;
      *(float4*)(cur + crow * 64 + cc + 4) = c1;
    }
    uint32_t h0, h1, h2, h3, l0, l1, l2, l3;
    split2(c0.x, c0.y, h0, l0); split2(c0.z, c0.w, h1, l1);
    split2(c1.x, c1.y, h2, l2); split2(c1.z, c1.w, h3, l3);
    uint32_t* ph = (uint32_t*)&CbfHi[crow][cc];
    ph[0] = h0; ph[1] = h1; ph[2] = h2; ph[3] = h3;
    uint32_t* pl = (uint32_t*)&CbfLo[crow][cc];
    pl[0] = l0; pl[1] = l1; pl[2] = l2; pl[3] = l3;
    float sq = c0.x*c0.x + c0.y*c0.y + c0.z*c0.z + c0.w*c0.w
             + c1.x*c1.x + c1.y*c1.y + c1.z*c1.z + c1.w*c1.w;
    sq += __shfl_xor(sq, 1); sq += __shfl_xor(sq, 2); sq += __shfl_xor(sq, 4);
    if ((t & 7) == 0) csqL[crow] = sq;
  }
  __syncthreads();  // CbfHi/CbfLo + csqL ready

  // ---- phase 1: dot = mfma(C, Wrow) over 4 k-chunks, split precision ----
  float16 dot0 = {0,0,0,0, 0,0,0,0, 0,0,0,0, 0,0,0,0};
  float16 dot1 = {0,0,0,0, 0,0,0,0, 0,0,0,0, 0,0,0,0};
#pragma unroll
  for (int ko = 0; ko < 4; ++ko) {
    float4 a = (ko == 0) ? wv0 : (ko == 1) ? wv2 : (ko == 2) ? wv4 : wv6;
    float4 b = (ko == 0) ? wv1 : (ko == 1) ? wv3 : (ko == 2) ? wv5 : wv7;
    uint32_t h0, h1, h2, h3, l0, l1, l2, l3;
    split2(a.x, a.y, h0, l0); split2(a.z, a.w, h1, l1);
    split2(b.x, b.y, h2, l2); split2(b.z, b.w, h3, l3);
    uint4v th = {h0, h1, h2, h3};
    uint4v tl = {l0, l1, l2, l3};
    short8 wHi = __builtin_bit_cast(short8, th);
    short8 wLo = __builtin_bit_cast(short8, tl);
#pragma unroll
    for (int nt = 0; nt < 2; ++nt) {
      const unsigned long long* ph = (const unsigned long long*)&CbfHi[nt * 32 + l31][ko * 16 + lh * 8];
      const unsigned long long* pl = (const unsigned long long*)&CbfLo[nt * 32 + l31][ko * 16 + lh * 8];
      ulong2v vh = {ph[0], ph[1]};
      ulong2v vl = {pl[0], pl[1]};
      short8 cHi = __builtin_bit_cast(short8, vh);
      short8 cLo = __builtin_bit_cast(short8, vl);
      float16& dd = nt ? dot1 : dot0;
      dd = __builtin_amdgcn_mfma_f32_32x32x16_bf16(cHi, wHi, dd, 0, 0, 0);
      dd = __builtin_amdgcn_mfma_f32_32x32x16_bf16(cLo, wHi, dd, 0, 0, 0);
      dd = __builtin_amdgcn_mfma_f32_32x32x16_bf16(cHi, wLo, dd, 0, 0, 0);
    }
  }

  // ---- prefetch phase-2 WT B-frags (latency hides under softmax) ----
  ushort8 wt[8];
  {
    const unsigned short* pwt =
        WT + (size_t)(ng * 32 + l31) * N_ROWS + rowBase + half * 128 + lh * 8;
#pragma unroll
    for (int c2 = 0; c2 < 4; ++c2)
#pragma unroll
      for (int kc = 0; kc < 2; ++kc)
        wt[c2 * 2 + kc] = *(const ushort8*)(pwt + c2 * 32 + kc * 16);
  }

  // ---- register softmax (row l31; lane^32 holds complementary clusters) ----
  float mx = -3.4e38f;
#pragma unroll
  for (int j = 0; j < 16; ++j) {
    const int cl = (j & 3) + 8 * (j >> 2) + 4 * lh;
    float d20 = fmaxf(fmaf(-2.f, dot0[j], w2 + csqL[cl]), 0.f);
    float d21 = fmaxf(fmaf(-2.f, dot1[j], w2 + csqL[cl + 32]), 0.f);
    float g0 = -sqrtf(d20), g1 = -sqrtf(d21);
    dot0[j] = g0; dot1[j] = g1;
    mx = fmaxf(mx, fmaxf(g0, g1));
  }
  mx = fmaxf(mx, __shfl_xor(mx, 32));
  float s = 0.f;
#pragma unroll
  for (int j = 0; j < 16; ++j) {
    float e0 = __expf(dot0[j] - mx), e1 = __expf(dot1[j] - mx);
    dot0[j] = e0; dot1[j] = e1;
    s += e0 + e1;
  }
  s += __shfl_xor(s, 32);
  float inv = __builtin_amdgcn_rcpf(s);

  // ---- attn out (iter 9) + pack attnT bf16 RNE for phase2 A-frags ----
  const int colA = wid * 32 + l31;
#pragma unroll
  for (int j = 0; j < 16; ++j) {
    const int cl = (j & 3) + 8 * (j >> 2) + 4 * lh;
    float a0 = dot0[j] * inv, a1 = dot1[j] * inv;
    if (writeAttn) {
      attn_out[(size_t)myrow * 64 + cl] = a0;
      attn_out[(size_t)myrow * 64 + cl + 32] = a1;
    }
    attnT[cl][colA] = (short)rne16(a0);
    attnT[cl + 32][colA] = (short)rne16(a1);
  }
  __syncthreads();  // attnT complete

  // ---- phase 2: U-quadrant (mg,ng), k-row half `half` ----
  float16 Uacc = {0,0,0,0, 0,0,0,0, 0,0,0,0, 0,0,0,0};
  const int arow = mg * 32 + l31;
#pragma unroll
  for (int c2 = 0; c2 < 4; ++c2) {
#pragma unroll
    for (int kc = 0; kc < 2; ++kc) {
      const unsigned long long* pa =
          (const unsigned long long*)&attnT[arow][half * 128 + c2 * 32 + kc * 16 + lh * 8];
      ulong2v va = {pa[0], pa[1]};
      short8 af = __builtin_bit_cast(short8, va);
      short8 bf = __builtin_bit_cast(short8, wt[c2 * 2 + kc]);
      Uacc = __builtin_amdgcn_mfma_f32_32x32x16_bf16(af, bf, Uacc, 0, 0, 0);
    }
  }

  // ---- sumA: column sums of attnT (bf16 RNE; denominator matches
  //      numerator's weights -> unbiased, noise ~1e-6 relative) ----
  {
    const int sk = t & 63, sg = t >> 6;
    float ssum = 0.f;
#pragma unroll
    for (int q2 = 0; q2 < 4; ++q2) {
      const uint32_t* pq = (const uint32_t*)&attnT[sk][sg * 32 + q2 * 8];
#pragma unroll
      for (int w = 0; w < 4; ++w) {
        uint32_t dv = pq[w];
        ssum += __uint_as_float(dv << 16) + __uint_as_float(dv & 0xffff0000u);
      }
    }
    red[t] = ssum;
  }
  __syncthreads();  // phase-2 A-reads + sumA reads done; red ready

  float* ured = (float*)&attnT[0][0];  // 16KB overlay on attnT
  if (half == 1) {
#pragma unroll
    for (int j = 0; j < 16; ++j) ured[(quad * 16 + j) * 64 + lane] = Uacc[j];
  }
  if (t < 64) {
    sumA[blk * 64 + t] = ((red[t] + red[t + 64]) + (red[t + 128] + red[t + 192])) +
                         ((red[t + 256] + red[t + 320]) + (red[t + 384] + red[t + 448]));
  }
  __syncthreads();
  if (half == 0) {
#pragma unroll
    for (int j = 0; j < 16; ++j) {
      float u = Uacc[j] + ured[(quad * 16 + j) * 64 + lane];
      const int k = mg * 32 + (j & 3) + 8 * (j >> 2) + 4 * lh;
      partial[((size_t)blk * 64 + k) * 64 + ng * 32 + l31] = u;
    }
  }
}

// Reduce 512 block partials -> newC (f64), norm partials. 128 blocks: (k, dhalf).
__global__ __launch_bounds__(256) void reduce_kernel(
    const float* __restrict__ partial, const float* __restrict__ sumAp,
    const float* __restrict__ curC, float* __restrict__ newC,
    double* __restrict__ normpart) {
  const int k = blockIdx.x >> 1, dh = blockIdx.x & 1;
  const int t = threadIdx.x;
  const int d = dh * 32 + (t & 31), q = t >> 5;
  double acc = 0.0;
  for (int b = q * 64; b < q * 64 + 64; ++b)
    acc += (double)partial[((size_t)b * 64 + k) * 64 + d];
  __shared__ double sh[256];
  __shared__ double sh2[256];
  sh[t] = acc;
  sh2[t] = (double)sumAp[t * 64 + k] + (double)sumAp[(t + 256) * 64 + k];
  __syncthreads();
  for (int s = 128; s >= 1; s >>= 1) {
    if (t < s) sh2[t] += sh2[t + s];
    __syncthreads();
  }
  if (t < 32) {
    double tot = ((sh[t] + sh[t + 32]) + (sh[t + 64] + sh[t + 96])) +
                 ((sh[t + 128] + sh[t + 160]) + (sh[t + 192] + sh[t + 224]));
    float nc = (float)(tot / sh2[0]);
    newC[k * 64 + d] = nc;
    double diff = (double)curC[k * 64 + d] - (double)nc;
    sh[t] = diff * diff;
  }
  __syncthreads();
  if (t == 0) {
    double s = 0.0;
#pragma unroll
    for (int i = 0; i < 32; ++i) s += sh[i];
    normpart[blockIdx.x] = s;
  }
}

// Final select: clusters_out = (||cur9 - new9|| > eps) ? newC : cur
// (cur aliases clusters_out; per-element read-then-write is safe)
__global__ __launch_bounds__(256) void finalize_kernel(
    const double* __restrict__ np, const float* __restrict__ newC,
    const float* __restrict__ cur, float* __restrict__ clusters_out) {
  __shared__ double sh[64];
  __shared__ int sc;
  int t = threadIdx.x;
  if (t < 64) sh[t] = np[t] + np[t + 64];
  __syncthreads();
  if (t == 0) {
    double s = 0.0;
    for (int i = 0; i < 64; ++i) s += sh[i];
    sc = (s > 1.0e-8) ? 1 : 0;
  }
  __syncthreads();
  const float* src = sc ? newC : cur;
  for (int m = t; m < 4096; m += 256) {
    float v = src[m];
    clusters_out[m] = v;
  }
}

// compressed = attn @ clusters  (exact f32; reads only attn_out/clusters_out)
__global__ __launch_bounds__(256) void compress_kernel(
    const float* __restrict__ attn, const float* __restrict__ Cl,
    float* __restrict__ outC) {
  __shared__ float Csh[64 * 64];
  __shared__ float Ash[64 * 64];
  float4* Csh4 = (float4*)Csh;
  float4* Ash4 = (float4*)Ash;
  const int t = threadIdx.x;
  const int blk = blockIdx.x;
  const int rowBase = blk * ROWS_PB;
  const int rg = t >> 4, dg = t & 15;

  {
    const float4* gC = (const float4*)Cl;
#pragma unroll
    for (int q = 0; q < 4; ++q) {
      int m = t + 256 * q;
      Csh4[m ^ ((m >> 6) & 15)] = gC[m];
    }
  }

  for (int tile = 0; tile < 4; ++tile) {
    __syncthreads();
    {
      const float4* gA = (const float4*)(attn + (size_t)(rowBase + tile * 64) * KC);
#pragma unroll
      for (int q = 0; q < 4; ++q) {
        int m = t + 256 * q;
        Ash4[m ^ ((m >> 6) & 15)] = gA[m];
      }
    }
    __syncthreads();
    float acc[4][4] = {{0.f}};
#pragma unroll 4
    for (int c = 0; c < 16; ++c) {
      float4 av[4], cv[4];
#pragma unroll
      for (int i = 0; i < 4; ++i) av[i] = Ash4[((rg * 4 + i) * 16 + c) ^ rg];
#pragma unroll
      for (int j = 0; j < 4; ++j) cv[j] = Csh4[((c * 4 + j) * 16 + dg) ^ c];
#pragma unroll
      for (int i = 0; i < 4; ++i) {
        float a0 = fmaf(av[i].x, cv[0].x, acc[i][0]);
        a0 = fmaf(av[i].y, cv[1].x, a0);
        a0 = fmaf(av[i].z, cv[2].x, a0);
        acc[i][0] = fmaf(av[i].w, cv[3].x, a0);
        float a1 = fmaf(av[i].x, cv[0].y, acc[i][1]);
        a1 = fmaf(av[i].y, cv[1].y, a1);
        a1 = fmaf(av[i].z, cv[2].y, a1);
        acc[i][1] = fmaf(av[i].w, cv[3].y, a1);
        float a2 = fmaf(av[i].x, cv[0].z, acc[i][2]);
        a2 = fmaf(av[i].y, cv[1].z, a2);
        a2 = fmaf(av[i].z, cv[2].z, a2);
        acc[i][2] = fmaf(av[i].w, cv[3].z, a2);
        float a3 = fmaf(av[i].x, cv[0].w, acc[i][3]);
        a3 = fmaf(av[i].y, cv[1].w, a3);
        a3 = fmaf(av[i].z, cv[2].w, a3);
        acc[i][3] = fmaf(av[i].w, cv[3].w, a3);
      }
    }
    float4* gO = (float4*)(outC + (size_t)(rowBase + tile * 64) * DIM);
#pragma unroll
    for (int i = 0; i < 4; ++i)
      gO[(rg * 4 + i) * 16 + dg] = make_float4(acc[i][0], acc[i][1], acc[i][2], acc[i][3]);
  }
}

extern "C" void kernel_launch(void* const* d_in, const int* in_sizes, int n_in,
                              void* d_out, int out_size, void* d_ws, size_t ws_size,
                              hipStream_t stream) {
  (void)in_sizes; (void)n_in; (void)d_ws; (void)ws_size; (void)out_size;
  const float* W = (const float*)d_in[0];
  const float* Cinit = (const float*)d_in[1];
  float* ob = (float*)d_out;

  float* compressed = ob;                                  // [N, D]
  float* clusters_out = ob + (size_t)N_ROWS * DIM;         // [K, D]
  float* attn_out = ob + (size_t)N_ROWS * DIM + KC * DIM;  // [N, K]

  unsigned short* WT = (unsigned short*)d_out;             // 16MB at byte 0
  float* partial = ob + PARTIAL_OFF;
  float* sumAp = ob + SUMA_OFF;
  float* newC = ob + NEWC_OFF;
  float* cur = clusters_out;                               // 16KB exact
  double* normpart = (double*)((char*)d_out + NORM_BYTE_OFF);

  prep_kernel<<<NBLK, 256, 0, stream>>>(W, WT);

  for (int it = 0; it < 10; ++it) {
    dkm_iter<<<NBLK, 512, 0, stream>>>(W, WT, Cinit, newC, cur, normpart,
                                       partial, sumAp, attn_out,
                                       (it > 0) ? 1 : 0, (it == 9) ? 1 : 0);
    reduce_kernel<<<128, 256, 0, stream>>>(partial, sumAp, cur, newC, normpart);
  }
  finalize_kernel<<<1, 256, 0, stream>>>(normpart, newC, cur, clusters_out);
  compress_kernel<<<NBLK, 256, 0, stream>>>(attn_out, clusters_out, compressed);
}